// Round 11
// baseline (631.096 us; speedup 1.0000x reference)
//
#include <hip/hip_runtime.h>

// Problem constants
#define B_    64
#define C_    256
#define H_    32
#define W_    32
#define K_    1024
#define D_    256
#define HW_   1024
#define N_    65536
#define NELEM 16777216
#define DECAY_ 0.99f
#define OMD_   0.01f
#define EPS_   1e-5f
#define TAU_   0.12f        // fp64-rescan margin (>=13 sigma of int16-quant distance noise)

// d_out float offsets
#define OFF_LOSS    16777216
#define OFF_ENT     16777217
#define OFF_ENC     16777218   // 8B-aligned only
#define OFF_CLUSTER 83886082
#define OFF_NEWW    83887106
#define OFF_NEWEMB  84149250

// Scratch inside the (later overwritten) encodings output region [OFF_ENC, OFF_ENC+67108864):
// int8 hi/lo planes of q_x = clamp(round(-4096*x)), [N][D] bytes each, and packed
// int8 B-fragment tiles of q_e = clamp(round(4096*e)).
#define OFF_XH      (OFF_ENC + 2)              // 16MB plane (as floats: 4194304)
#define OFF_XL      (OFF_XH + 4194304)
#define OFF_EH      (OFF_XL + 4194304)         // packed B tiles, 256KB (65536 floats)
#define OFF_EL      (OFF_EH + 65536)
#define OFF_SORT2   (OFF_EL + 65536)           // sorted[65536] | offsets[1025] | cursor[1024]
// Scratch ends at rel 8587267 floats. Tail/head zero regions (16B-aligned float4):
#define ZTAIL_ABS   25364488                   // abs float idx, %4==0
#define ZTAIL_F4    14630398                   // float4s in tail
#define ZHEAD_F4    2146817                    // float4s in [rel 2, tail start)

typedef __attribute__((ext_vector_type(8)))  short short8;
typedef __attribute__((ext_vector_type(4)))  int   intx4;
typedef __attribute__((ext_vector_type(16))) int   intx16;

__global__ __launch_bounds__(64) void k_prep_e(const float* __restrict__ emb,
                                               signed char* __restrict__ eh,
                                               signed char* __restrict__ el,
                                               float* __restrict__ enorm) {
    // Packed B layout for mfma_i32_32x32x32_i8: tile(k>>5) of 8192 bytes =
    // [ds=8][h=2][c32=32][j=16]; element (k,d): ds=d>>5, h=(d>>4)&1, c32=k&31, j=d&15.
    const int k = blockIdx.x;
    const int t = threadIdx.x;       // handles d = 4t .. 4t+3 (same ds, same h)
    float4 v = ((const float4*)(emb + (size_t)k * D_))[t];
    float s = v.x * v.x + v.y * v.y + v.z * v.z + v.w * v.w;
    signed char hq[4], lq[4];
    {
        float f[4] = {v.x, v.y, v.z, v.w};
        #pragma unroll
        for (int j = 0; j < 4; ++j) {
            int q = (int)rintf(f[j] * 4096.0f);      // scale 2^12 (max|e|*4096 ~ 21k < clamp)
            q = q < -32640 ? -32640 : (q > 32639 ? 32639 : q);
            int hh = (q + 128) >> 8;
            hq[j] = (signed char)hh;
            lq[j] = (signed char)(q - (hh << 8));
        }
    }
    size_t o = (size_t)(k >> 5) * 8192 + (size_t)(t >> 3) * 1024
             + (size_t)((t >> 2) & 1) * 512 + (size_t)(k & 31) * 16 + (t & 3) * 4;
    *(char4*)(eh + o) = make_char4(hq[0], hq[1], hq[2], hq[3]);
    *(char4*)(el + o) = make_char4(lq[0], lq[1], lq[2], lq[3]);
    #pragma unroll
    for (int off = 32; off > 0; off >>= 1) s += __shfl_down(s, off);
    if (t == 0) enorm[k] = s;      // exact fp32 norm of ORIGINAL e
}

// NCHW -> n-major int8 hi/lo split of q = round(-4096*x). Tile 32 d x 256 n per block.
// Folded zero-init: dw[262144], counts/flagcount/losssum, cursor[1024].
__global__ __launch_bounds__(256) void k_prep_x(const float* __restrict__ inp,
                                                signed char* __restrict__ xh,
                                                signed char* __restrict__ xl,
                                                float* __restrict__ dw,
                                                int* __restrict__ small_,
                                                int* __restrict__ cursor) {
    __shared__ float tile[32][257];
    const int tid = threadIdx.x;
    const int bid = blockIdx.x;            // 2048 blocks: b(64) x hwtile(4) x dtile(8)
    if (bid < 1024) {
        int g = bid * 256 + tid;
        dw[g] = 0.0f;
        if (g < 1026) small_[g] = 0;
        if (bid < 4) cursor[bid * 256 + tid] = 0;
    }
    const int dt = bid & 7;
    const int ht = (bid >> 3) & 3;
    const int b = bid >> 5;
    const int d0 = dt * 32;
    const int hw0 = ht * 256;
    const float* src = inp + (size_t)b * (C_ * HW_) + (size_t)d0 * HW_ + hw0;
    #pragma unroll
    for (int i = 0; i < 8; ++i) {
        int idx4 = i * 256 + tid;
        int dl = idx4 >> 6;
        int nl4 = (idx4 & 63) * 4;
        float4 v = *(const float4*)(src + (size_t)dl * HW_ + nl4);
        tile[dl][nl4] = v.x; tile[dl][nl4 + 1] = v.y;
        tile[dl][nl4 + 2] = v.z; tile[dl][nl4 + 3] = v.w;
    }
    __syncthreads();
    const int nbase = b * HW_ + hw0;
    #pragma unroll
    for (int i = 0; i < 4; ++i) {
        int f8 = i * 256 + tid;            // 1024 items of 8 d
        int nl = f8 >> 2;
        int dpos = (f8 & 3) * 8;
        union { signed char c[8]; long long v; } ph, pl;
        #pragma unroll
        for (int j = 0; j < 8; ++j) {
            int q = (int)rintf(-4096.0f * tile[dpos + j][nl]);
            q = q < -32640 ? -32640 : (q > 32639 ? 32639 : q);
            int hh = (q + 128) >> 8;
            ph.c[j] = (signed char)hh;
            pl.c[j] = (signed char)(q - (hh << 8));
        }
        size_t o = (size_t)(nbase + nl) * D_ + d0 + dpos;
        *(long long*)(xh + o) = ph.v;
        *(long long*)(xl + o) = pl.v;
    }
}

// Stage one 8KB+8KB packed int8 B tile into LDS: 256 threads x 2 iters x 2 arrays
// = exactly 4 gload_lds instructions per thread.
__device__ __forceinline__ void stage_tile8(const signed char* __restrict__ gh,
                                            const signed char* __restrict__ gl,
                                            signed char* sh, signed char* sl,
                                            int tid) {
    #pragma unroll
    for (int i = 0; i < 2; ++i) {
        __builtin_amdgcn_global_load_lds(
            (const __attribute__((address_space(1))) unsigned int*)(gh + i * 4096 + tid * 16),
            (__attribute__((address_space(3))) unsigned int*)(sh + i * 4096 + tid * 16),
            16, 0, 0);
        __builtin_amdgcn_global_load_lds(
            (const __attribute__((address_space(1))) unsigned int*)(gl + i * 4096 + tid * 16),
            (__attribute__((address_space(3))) unsigned int*)(sl + i * 4096 + tid * 16),
            16, 0, 0);
    }
}

// i8-MFMA distance argmin (mfma_i32_32x32x32_i8, K=32): 32 rows/wave, 32 cols/K-step.
// q_x = -4096x, q_e = 4096e as int16 = 256*hi + lo (int8 planes). Four i32 partial
// dots (hh, hl, lh, ll) are EXACT; combine in fp32: dot = (hh*65536 + (hl+lh)*256
// + ll) * 2^-23. Counted-vmcnt barrier: 4 gloads then 4 clamped zero-stores -> vmcnt(4).
__global__ __launch_bounds__(256, 2) void k_argmin(
    const signed char* __restrict__ xh, const signed char* __restrict__ xl,
    const signed char* __restrict__ eh, const signed char* __restrict__ el,
    const float* __restrict__ enorm, int* __restrict__ idx_out,
    int* __restrict__ flagcount, int* __restrict__ flaglist,
    float4* __restrict__ encz, int* __restrict__ counts)
{
    __shared__ __align__(16) signed char smem[2][2][8192];   // 32KB
    const int tid = threadIdx.x;
    const int w = tid >> 6;
    const int lane = tid & 63;
    const int c32 = lane & 31;
    const int h = lane >> 5;
    const int r0 = blockIdx.x * 128 + w * 32;
    const int gtid = blockIdx.x * 256 + tid;      // 0..131071
    const float4 z4 = make_float4(0.f, 0.f, 0.f, 0.f);

    // A fragments: row = lane&31, k = h*16 + j (16 consecutive bytes per ds-chunk)
    intx4 Ah[8], Al[8];
    {
        const signed char* pa = xh + (size_t)(r0 + c32) * D_ + h * 16;
        const signed char* pl = xl + (size_t)(r0 + c32) * D_ + h * 16;
        #pragma unroll
        for (int ds = 0; ds < 8; ++ds) {
            Ah[ds] = *(const intx4*)(pa + ds * 32);
            Al[ds] = *(const intx4*)(pl + ds * 32);
        }
    }

    float b1[16], b2[16];
    int bi[16];
    #pragma unroll
    for (int i = 0; i < 16; ++i) { b1[i] = 3.0e38f; b2[i] = 3.0e38f; bi[i] = 0; }

    // prologue: stage tile 0 into buffer 0
    stage_tile8(eh, el, &smem[0][0][0], &smem[0][1][0], tid);
    __syncthreads();

    // per-lane B read base: col = lane&31 -> h*512 + c32*16 bytes
    const int rb = (h << 9) + (c32 << 4);

    int cb = 0;
    for (int ct = 0; ct < 32; ++ct) {
        if (ct + 1 < 32) {
            stage_tile8(eh + (size_t)(ct + 1) * 8192, el + (size_t)(ct + 1) * 8192,
                        &smem[cb ^ 1][0][0], &smem[cb ^ 1][1][0], tid);
        }
        // pin issue order: all 4 gloads BEFORE the 4 stores (vmcnt retires in order)
        __builtin_amdgcn_sched_barrier(0);
        // background zero-fill of the encodings tail: EXACTLY 4 stores, clamped
        #pragma unroll
        for (int jj = 0; jj < 4; ++jj) {
            int zi = (ct * 4 + jj) * 131072 + gtid;
            zi = (zi < ZTAIL_F4) ? zi : (ZTAIL_F4 - 1);
            encz[zi] = z4;
        }
        const int col = ct * 32 + c32;
        const float en = enorm[col];
        const signed char* sbh = &smem[cb][0][rb];
        const signed char* sbl = &smem[cb][1][rb];
        intx16 hh, m1, m2, ll;
        #pragma unroll
        for (int i = 0; i < 16; ++i) { hh[i] = 0; m1[i] = 0; m2[i] = 0; ll[i] = 0; }
        #pragma unroll
        for (int ds = 0; ds < 8; ++ds) {
            intx4 bh = *(const intx4*)(sbh + ds * 1024);
            intx4 bl = *(const intx4*)(sbl + ds * 1024);
            hh = __builtin_amdgcn_mfma_i32_32x32x32_i8(Ah[ds], bh, hh, 0, 0, 0);
            m1 = __builtin_amdgcn_mfma_i32_32x32x32_i8(Ah[ds], bl, m1, 0, 0, 0);
            m2 = __builtin_amdgcn_mfma_i32_32x32x32_i8(Al[ds], bh, m2, 0, 0, 0);
            ll = __builtin_amdgcn_mfma_i32_32x32x32_i8(Al[ds], bl, ll, 0, 0, 0);
        }
        #pragma unroll
        for (int r = 0; r < 16; ++r) {
            float dot = (float)hh[r] * 65536.0f + (float)(m1[r] + m2[r]) * 256.0f
                      + (float)ll[r];
            float v = en + dot * 1.1920928955078125e-07f;   // * 2^-23
            bool lt = v < b1[r];
            float nb2 = lt ? b1[r] : fminf(v, b2[r]);
            b2[r] = nb2;
            b1[r] = lt ? v : b1[r];
            bi[r] = lt ? col : bi[r];
        }
        // counted-vmcnt barrier: staging loads done, newest 4 stores stay in flight
        asm volatile("s_waitcnt vmcnt(4)" ::: "memory");
        __builtin_amdgcn_sched_barrier(0);
        __builtin_amdgcn_s_barrier();
        __builtin_amdgcn_sched_barrier(0);
        cb ^= 1;
    }

    // LDS is dead: reuse first 4KB as the block histogram
    int* histL = (int*)&smem[0][0][0];
    #pragma unroll
    for (int j = 0; j < 4; ++j) histL[tid + j * 256] = 0;
    __syncthreads();

    #pragma unroll
    for (int r = 0; r < 16; ++r) {
        float B1 = b1[r], B2 = b2[r];
        int Bi = bi[r];
        #pragma unroll
        for (int mask = 1; mask <= 16; mask <<= 1) {
            float v1 = __shfl_xor(B1, mask);
            float v2 = __shfl_xor(B2, mask);
            int i1 = __shfl_xor(Bi, mask);
            if (v1 < B1 || (v1 == B1 && i1 < Bi)) {
                B2 = fminf(fminf(B1, B2), v2);
                B1 = v1; Bi = i1;
            } else {
                B2 = fminf(B2, fminf(v1, v2));
            }
        }
        if (c32 == 0) {
            int row = r0 + (r & 3) + 4 * h + 8 * (r >> 2);
            idx_out[row] = Bi;
            atomicAdd(&histL[Bi], 1);
            if (B2 - B1 < TAU_) {
                int p = atomicAdd(flagcount, 1);
                flaglist[p] = row;
            }
        }
    }
    __syncthreads();
    #pragma unroll
    for (int j = 0; j < 4; ++j) {
        int v = histL[tid + j * 256];
        if (v) atomicAdd(&counts[tid + j * 256], v);
    }
}

// Exact fp64 rescan of flagged (near-tie) rows; incrementally fixes counts.
__global__ __launch_bounds__(256) void k_rescan(
    const float* __restrict__ inp, const float* __restrict__ emb,
    const int* __restrict__ flagcount, const int* __restrict__ flaglist,
    int* __restrict__ idx_out, int* __restrict__ counts)
{
    __shared__ double xd[256];
    __shared__ double sv[256];
    __shared__ int si[256];
    const int tid = threadIdx.x;
    const int nflag = *flagcount;
    for (int f = blockIdx.x; f < nflag; f += gridDim.x) {
        int n = flaglist[f];
        int b = n >> 10, nn = n & 1023;
        xd[tid] = (double)inp[(size_t)b * (C_ * HW_) + (size_t)tid * HW_ + nn];
        __syncthreads();
        double bv = 1e300; int bi = 0;
        for (int k = tid; k < K_; k += 256) {
            const float* ep = emb + (size_t)k * D_;
            double dot = 0.0, en = 0.0;
            for (int d = 0; d < D_; ++d) {
                double e = (double)ep[d];
                dot = fma(xd[d], e, dot);
                en  = fma(e, e, en);
            }
            double v = en - 2.0 * dot;
            if (v < bv) { bv = v; bi = k; }
        }
        sv[tid] = bv; si[tid] = bi;
        __syncthreads();
        for (int s = 128; s > 0; s >>= 1) {
            if (tid < s) {
                if (sv[tid + s] < sv[tid] || (sv[tid + s] == sv[tid] && si[tid + s] < si[tid])) {
                    sv[tid] = sv[tid + s]; si[tid] = si[tid + s];
                }
            }
            __syncthreads();
        }
        if (tid == 0) {
            int old = idx_out[n];
            int nw = si[0];
            if (nw != old) {
                idx_out[n] = nw;
                atomicAdd(&counts[old], -1);
                atomicAdd(&counts[nw], 1);
            }
        }
        __syncthreads();
    }
}

// Block-aggregated scatter with local exclusive scan of final counts.
__global__ __launch_bounds__(256) void k_scatter(const int* __restrict__ idx,
                                                 const int* __restrict__ counts,
                                                 int* __restrict__ cursor,
                                                 int* __restrict__ sorted,
                                                 int* __restrict__ offsets) {
    __shared__ int sc[1024];
    __shared__ int hc[1024];
    __shared__ int hb[1024];
    const int tid = threadIdx.x;
    const int base = blockIdx.x * 1024;
    int creg[4];
    #pragma unroll
    for (int j = 0; j < 4; ++j) {
        int k = tid + j * 256;
        creg[j] = counts[k];
        sc[k] = creg[j];
        hc[k] = 0;
    }
    __syncthreads();
    for (int off = 1; off < 1024; off <<= 1) {
        int t0[4];
        #pragma unroll
        for (int j = 0; j < 4; ++j) {
            int k = tid + j * 256;
            t0[j] = (k >= off) ? sc[k - off] : 0;
        }
        __syncthreads();
        #pragma unroll
        for (int j = 0; j < 4; ++j) sc[tid + j * 256] += t0[j];
        __syncthreads();
    }
    #pragma unroll
    for (int j = 0; j < 4; ++j) {
        int k = tid + j * 256;
        sc[k] -= creg[j];
    }
    __syncthreads();
    if (blockIdx.x == 0) {
        #pragma unroll
        for (int j = 0; j < 4; ++j) {
            int k = tid + j * 256;
            offsets[k] = sc[k];
            if (k == 1023) offsets[1024] = sc[1023] + creg[j];
        }
    }
    int myk[4], myn[4];
    #pragma unroll
    for (int j = 0; j < 4; ++j) {
        int n = base + j * 256 + tid;
        myn[j] = n;
        myk[j] = idx[n];
        atomicAdd(&hc[myk[j]], 1);
    }
    __syncthreads();
    #pragma unroll
    for (int j = 0; j < 4; ++j) {
        int kk = tid + j * 256;
        int c = hc[kk];
        hb[kk] = c ? atomicAdd(&cursor[kk], c) : 0;
    }
    __syncthreads();
    #pragma unroll
    for (int j = 0; j < 4; ++j) hc[tid + j * 256] = 0;
    __syncthreads();
    #pragma unroll
    for (int j = 0; j < 4; ++j) {
        int p = sc[myk[j]] + hb[myk[j]] + atomicAdd(&hc[myk[j]], 1);
        sorted[p] = myn[j];
    }
}

// Balanced segmented dw reduction from int8 planes: EXACT int32 accumulation of
// q = 256*xh + xl (= -4096x); dw = -sum(q)/4096 = sum(x).
__global__ __launch_bounds__(256) void k_dwg(const signed char* __restrict__ xh,
                                             const signed char* __restrict__ xl,
                                             const int* __restrict__ sorted,
                                             const int* __restrict__ idx,
                                             const int* __restrict__ offsets,
                                             float* __restrict__ dw) {
    const int lane = threadIdx.x & 63;
    const int wid = threadIdx.x >> 6;
    const int wbase = (blockIdx.x * 4 + wid) * 64;

    int myn = sorted[wbase + lane];
    int myk = idx[myn];

    int4 acc = make_int4(0, 0, 0, 0);
    int cur = __shfl(myk, 0);
    const float sc = -1.0f / 4096.0f;

    #pragma unroll 8
    for (int i = 0; i < 64; ++i) {
        int n = __shfl(myn, i);
        int k = __shfl(myk, i);
        if (k != cur) {
            bool full = (offsets[cur] >= wbase) && (offsets[cur + 1] <= wbase + 64);
            float* dwk = dw + (size_t)cur * D_ + lane * 4;
            if (full) {
                ((float2*)dwk)[0] = make_float2(sc * acc.x, sc * acc.y);
                ((float2*)dwk)[1] = make_float2(sc * acc.z, sc * acc.w);
            } else {
                atomicAdd(dwk + 0, sc * acc.x);
                atomicAdd(dwk + 1, sc * acc.y);
                atomicAdd(dwk + 2, sc * acc.z);
                atomicAdd(dwk + 3, sc * acc.w);
            }
            acc = make_int4(0, 0, 0, 0);
            cur = k;
        }
        size_t o = (size_t)n * D_ + lane * 4;
        char4 hx = *(const char4*)(xh + o);
        char4 lx = *(const char4*)(xl + o);
        acc.x += ((int)hx.x << 8) + (int)lx.x;
        acc.y += ((int)hx.y << 8) + (int)lx.y;
        acc.z += ((int)hx.z << 8) + (int)lx.z;
        acc.w += ((int)hx.w << 8) + (int)lx.w;
    }
    {
        bool full = (offsets[cur] >= wbase) && (offsets[cur + 1] <= wbase + 64);
        float* dwk = dw + (size_t)cur * D_ + lane * 4;
        if (full) {
            ((float2*)dwk)[0] = make_float2(sc * acc.x, sc * acc.y);
            ((float2*)dwk)[1] = make_float2(sc * acc.z, sc * acc.w);
        } else {
            atomicAdd(dwk + 0, sc * acc.x);
            atomicAdd(dwk + 1, sc * acc.y);
            atomicAdd(dwk + 2, sc * acc.z);
            atomicAdd(dwk + 3, sc * acc.w);
        }
    }
}

// Quantize + loss (LDS-transposed embedding gather) + folded head-zero.
__global__ __launch_bounds__(256) void k_quant(
    const float* __restrict__ inp, const float* __restrict__ emb,
    const int* __restrict__ idx, float* __restrict__ outp, float* __restrict__ losssum,
    float* __restrict__ enc)
{
    __shared__ float qt[64][260];
    __shared__ int karr[64];
    __shared__ float red[256];
    const int tid = threadIdx.x;
    const int bid = blockIdx.x;        // 1024 blocks: b(64) x hwtile(16)
    const int b = bid >> 4;
    const int ht = bid & 15;
    const int base_n = b * HW_ + ht * 64;

    {
        const float4 z4 = make_float4(0.f, 0.f, 0.f, 0.f);
        float4* pz = (float4*)(enc + 2);
        int t = bid * 256 + tid;       // 262144 threads
        #pragma unroll
        for (int it = 0; it < 9; ++it) {
            int i = it * 262144 + t;
            if (i < ZHEAD_F4) pz[i] = z4;
        }
        if (t == 0) { enc[0] = 0.f; enc[1] = 0.f; enc[67108862] = 0.f; enc[67108863] = 0.f; }
    }

    if (tid < 64) karr[tid] = idx[base_n + tid];
    __syncthreads();

    #pragma unroll
    for (int it = 0; it < 16; ++it) {
        int f = it * 256 + tid;
        int r = f >> 6;
        int c4 = (f & 63) << 2;
        float4 v = ((const float4*)emb)[karr[r] * 64 + (c4 >> 2)];
        *(float4*)(&qt[r][c4]) = v;
    }
    __syncthreads();

    float s = 0.0f;
    #pragma unroll
    for (int it = 0; it < 16; ++it) {
        int f = it * 256 + tid;
        int c = f >> 4;
        int hl = (f & 15) << 2;
        int g = b * 65536 + c * 256 + ht * 16 + (hl >> 2);
        float4 x = ((const float4*)inp)[g];
        float q0 = qt[hl + 0][c];
        float q1 = qt[hl + 1][c];
        float q2 = qt[hl + 2][c];
        float q3 = qt[hl + 3][c];
        float d0 = q0 - x.x, d1 = q1 - x.y, d2 = q2 - x.z, d3 = q3 - x.w;
        ((float4*)outp)[g] = make_float4(x.x + d0, x.y + d1, x.z + d2, x.w + d3);
        s += d0 * d0 + d1 * d1 + d2 * d2 + d3 * d3;
    }
    red[tid] = s;
    __syncthreads();
    for (int t = 128; t > 0; t >>= 1) {
        if (tid < t) red[tid] += red[tid + t];
        __syncthreads();
    }
    if (tid == 0) atomicAdd(losssum, red[0]);
}

// Final fused kernel: cluster EMA, ema_w/new_embedding, loss+entropy, one-hot writes.
__global__ __launch_bounds__(256) void k_fin(
    const float* __restrict__ ema_cs, const int* __restrict__ counts,
    const float* __restrict__ losssum, const float* __restrict__ ema_w,
    const int* __restrict__ idx,
    float* __restrict__ neww, float* __restrict__ newemb,
    float* __restrict__ out_cluster, float* __restrict__ out_loss,
    float* __restrict__ out_ent, float* __restrict__ enc)
{
    __shared__ float sraw[1024];
    __shared__ float red[256];
    __shared__ float sclv;
    const int tid = threadIdx.x;
    const int bid = blockIdx.x;
    float part = 0.f;
    float ent = 0.f;
    #pragma unroll
    for (int j = 0; j < 4; ++j) {
        int k = tid + j * 256;
        float cnt = (float)counts[k];
        float raw = ema_cs[k] * DECAY_ + OMD_ * cnt;
        sraw[k] = raw;
        part += raw;
        float p = cnt * (1.0f / 65536.0f);
        ent += p * logf(p + 1e-10f);
    }
    red[tid] = part;
    __syncthreads();
    for (int t = 128; t > 0; t >>= 1) {
        if (tid < t) red[tid] += red[tid + t];
        __syncthreads();
    }
    float nsum = red[0];
    __syncthreads();
    red[tid] = ent;
    __syncthreads();
    for (int t = 128; t > 0; t >>= 1) {
        if (tid < t) red[tid] += red[tid + t];
        __syncthreads();
    }
    if (tid == 0) {
        float clv = (sraw[bid] + EPS_) / (nsum + 1024.0f * EPS_) * nsum;
        sclv = clv;
        out_cluster[bid] = clv;
        if (bid == 0) {
            out_ent[0] = -red[0];
            out_loss[0] = 0.25f * losssum[0] * (1.0f / 16777216.0f);
        }
    }
    __syncthreads();
    float clv = sclv;
    int g = bid * 256 + tid;
    float w = ema_w[g] * DECAY_ + OMD_ * neww[g];
    neww[g] = w;
    newemb[g] = w / clv;
    if (tid < 64) {
        int n = bid * 64 + tid;
        enc[(size_t)n * 1024 + idx[n]] = 1.0f;
    }
}

extern "C" void kernel_launch(void* const* d_in, const int* in_sizes, int n_in,
                              void* d_out, int out_size, void* d_ws, size_t ws_size,
                              hipStream_t stream)
{
    const float* inp    = (const float*)d_in[0];
    const float* emb    = (const float*)d_in[1];
    const float* ema_cs = (const float*)d_in[2];
    const float* ema_w  = (const float*)d_in[3];

    float* out0        = (float*)d_out;
    float* out_loss    = out0 + OFF_LOSS;
    float* out_ent     = out0 + OFF_ENT;
    float* out_enc     = out0 + OFF_ENC;
    float* out_cluster = out0 + OFF_CLUSTER;
    float* out_neww    = out0 + OFF_NEWW;
    float* out_newemb  = out0 + OFF_NEWEMB;

    signed char* ws_xh = (signed char*)(out0 + OFF_XH);
    signed char* ws_xl = (signed char*)(out0 + OFF_XL);
    signed char* ws_eh = (signed char*)(out0 + OFF_EH);
    signed char* ws_el = (signed char*)(out0 + OFF_EL);
    int*   ws_sorted  = (int*)(out0 + OFF_SORT2);
    int*   ws_offsets = ws_sorted + 65536;
    int*   ws_cursor  = ws_offsets + 1025;

    int*   ws_idx    = (int*)d_ws;
    int*   ws_counts = ws_idx + 65536;
    int*   ws_flagc  = ws_idx + 66560;
    float* ws_loss   = (float*)(ws_idx + 66561);
    int*   ws_flagl  = ws_idx + 66562;
    float* ws_enorm  = (float*)(ws_idx + 132098);

    float4* encz = (float4*)(out0 + ZTAIL_ABS);

    k_prep_e <<<1024, 64, 0, stream>>>(emb, ws_eh, ws_el, ws_enorm);
    k_prep_x <<<2048, 256, 0, stream>>>(inp, ws_xh, ws_xl, out_neww, ws_counts, ws_cursor);
    k_argmin <<<512, 256, 0, stream>>>(ws_xh, ws_xl, ws_eh, ws_el, ws_enorm,
                                       ws_idx, ws_flagc, ws_flagl, encz, ws_counts);
    k_rescan <<<256, 256, 0, stream>>>(inp, emb, ws_flagc, ws_flagl, ws_idx, ws_counts);
    k_scatter<<<64, 256, 0, stream>>>(ws_idx, ws_counts, ws_cursor, ws_sorted, ws_offsets);
    k_dwg    <<<256, 256, 0, stream>>>(ws_xh, ws_xl, ws_sorted, ws_idx, ws_offsets, out_neww);
    k_quant  <<<1024, 256, 0, stream>>>(inp, emb, ws_idx, out0, ws_loss, out_enc);
    k_fin    <<<1024, 256, 0, stream>>>(ema_cs, ws_counts, ws_loss, ema_w, ws_idx,
                                        out_neww, out_newemb, out_cluster, out_loss,
                                        out_ent, out_enc);
}

// Round 12
// 604.059 us; speedup vs baseline: 1.0448x; 1.0448x over previous
//
#include <hip/hip_runtime.h>

// Problem constants
#define B_    64
#define C_    256
#define H_    32
#define W_    32
#define K_    1024
#define D_    256
#define HW_   1024
#define N_    65536
#define NELEM 16777216
#define DECAY_ 0.99f
#define OMD_   0.01f
#define EPS_   1e-5f
#define TAU_   0.05f        // fp64-rescan margin (~15 sigma of int16-quant distance noise)

// d_out float offsets
#define OFF_LOSS    16777216
#define OFF_ENT     16777217
#define OFF_ENC     16777218   // 8B-aligned only
#define OFF_CLUSTER 83886082
#define OFF_NEWW    83887106
#define OFF_NEWEMB  84149250

// Scratch inside the (later overwritten) encodings output region [OFF_ENC, OFF_ENC+67108864):
// int8 hi/lo planes of q_x = clamp(round(-4096*x)), [N][D] bytes each, and packed
// int8 B-fragment tiles of q_e = clamp(round(4096*e)).
#define OFF_XH      (OFF_ENC + 2)              // 16MB plane (as floats: 4194304)
#define OFF_XL      (OFF_XH + 4194304)
#define OFF_EH      (OFF_XL + 4194304)         // packed B tiles, 256KB (65536 floats)
#define OFF_EL      (OFF_EH + 65536)
#define OFF_SORT2   (OFF_EL + 65536)           // sorted[65536] | offsets[1025] | cursor[1024]
// Scratch ends at rel 8587267 floats. Tail/head zero regions (16B-aligned float4):
#define ZTAIL_ABS   25364488                   // abs float idx, %4==0
#define ZTAIL_F4    14630398                   // float4s in tail
#define ZHEAD_F4    2146817                    // float4s in [rel 2, tail start)

typedef __attribute__((ext_vector_type(8)))  short short8;
typedef __attribute__((ext_vector_type(4)))  int   intx4;
typedef __attribute__((ext_vector_type(16))) int   intx16;

__global__ __launch_bounds__(64) void k_prep_e(const float* __restrict__ emb,
                                               signed char* __restrict__ eh,
                                               signed char* __restrict__ el,
                                               float* __restrict__ enorm,
                                               double* __restrict__ enorm64) {
    // Packed B layout for mfma_i32_32x32x32_i8: tile(k>>5) of 8192 bytes =
    // [ds=8][h=2][c32=32][j=16]; element (k,d): ds=d>>5, h=(d>>4)&1, c32=k&31, j=d&15.
    const int k = blockIdx.x;
    const int t = threadIdx.x;       // handles d = 4t .. 4t+3 (same ds, same h)
    float4 v = ((const float4*)(emb + (size_t)k * D_))[t];
    float s = v.x * v.x + v.y * v.y + v.z * v.z + v.w * v.w;
    double s64 = (double)v.x * v.x + (double)v.y * v.y
               + (double)v.z * v.z + (double)v.w * v.w;
    signed char hq[4], lq[4];
    {
        float f[4] = {v.x, v.y, v.z, v.w};
        #pragma unroll
        for (int j = 0; j < 4; ++j) {
            int q = (int)rintf(f[j] * 4096.0f);      // scale 2^12 (max|e|*4096 ~ 21k < clamp)
            q = q < -32640 ? -32640 : (q > 32639 ? 32639 : q);
            int hh = (q + 128) >> 8;
            hq[j] = (signed char)hh;
            lq[j] = (signed char)(q - (hh << 8));
        }
    }
    size_t o = (size_t)(k >> 5) * 8192 + (size_t)(t >> 3) * 1024
             + (size_t)((t >> 2) & 1) * 512 + (size_t)(k & 31) * 16 + (t & 3) * 4;
    *(char4*)(eh + o) = make_char4(hq[0], hq[1], hq[2], hq[3]);
    *(char4*)(el + o) = make_char4(lq[0], lq[1], lq[2], lq[3]);
    #pragma unroll
    for (int off = 32; off > 0; off >>= 1) {
        s += __shfl_down(s, off);
        s64 += __shfl_down(s64, off);
    }
    if (t == 0) { enorm[k] = s; enorm64[k] = s64; }
}

// NCHW -> n-major int8 hi/lo split of q = round(-4096*x). Tile 32 d x 256 n per block.
// Folded zero-init: dw[262144], counts/flagcount/losssum, cursor[1024].
__global__ __launch_bounds__(256) void k_prep_x(const float* __restrict__ inp,
                                                signed char* __restrict__ xh,
                                                signed char* __restrict__ xl,
                                                float* __restrict__ dw,
                                                int* __restrict__ small_,
                                                int* __restrict__ cursor) {
    __shared__ float tile[32][257];
    const int tid = threadIdx.x;
    const int bid = blockIdx.x;            // 2048 blocks: b(64) x hwtile(4) x dtile(8)
    if (bid < 1024) {
        int g = bid * 256 + tid;
        dw[g] = 0.0f;
        if (g < 1026) small_[g] = 0;
        if (bid < 4) cursor[bid * 256 + tid] = 0;
    }
    const int dt = bid & 7;
    const int ht = (bid >> 3) & 3;
    const int b = bid >> 5;
    const int d0 = dt * 32;
    const int hw0 = ht * 256;
    const float* src = inp + (size_t)b * (C_ * HW_) + (size_t)d0 * HW_ + hw0;
    #pragma unroll
    for (int i = 0; i < 8; ++i) {
        int idx4 = i * 256 + tid;
        int dl = idx4 >> 6;
        int nl4 = (idx4 & 63) * 4;
        float4 v = *(const float4*)(src + (size_t)dl * HW_ + nl4);
        tile[dl][nl4] = v.x; tile[dl][nl4 + 1] = v.y;
        tile[dl][nl4 + 2] = v.z; tile[dl][nl4 + 3] = v.w;
    }
    __syncthreads();
    const int nbase = b * HW_ + hw0;
    #pragma unroll
    for (int i = 0; i < 4; ++i) {
        int f8 = i * 256 + tid;            // 1024 items of 8 d
        int nl = f8 >> 2;
        int dpos = (f8 & 3) * 8;
        union { signed char c[8]; long long v; } ph, pl;
        #pragma unroll
        for (int j = 0; j < 8; ++j) {
            int q = (int)rintf(-4096.0f * tile[dpos + j][nl]);
            q = q < -32640 ? -32640 : (q > 32639 ? 32639 : q);
            int hh = (q + 128) >> 8;
            ph.c[j] = (signed char)hh;
            pl.c[j] = (signed char)(q - (hh << 8));
        }
        size_t o = (size_t)(nbase + nl) * D_ + d0 + dpos;
        *(long long*)(xh + o) = ph.v;
        *(long long*)(xl + o) = pl.v;
    }
}

// Stage one 8KB+8KB packed int8 B tile into LDS: 256 threads x 2 iters x 2 arrays
// = exactly 4 gload_lds instructions per thread.
__device__ __forceinline__ void stage_tile8(const signed char* __restrict__ gh,
                                            const signed char* __restrict__ gl,
                                            signed char* sh, signed char* sl,
                                            int tid) {
    #pragma unroll
    for (int i = 0; i < 2; ++i) {
        __builtin_amdgcn_global_load_lds(
            (const __attribute__((address_space(1))) unsigned int*)(gh + i * 4096 + tid * 16),
            (__attribute__((address_space(3))) unsigned int*)(sh + i * 4096 + tid * 16),
            16, 0, 0);
        __builtin_amdgcn_global_load_lds(
            (const __attribute__((address_space(1))) unsigned int*)(gl + i * 4096 + tid * 16),
            (__attribute__((address_space(3))) unsigned int*)(sl + i * 4096 + tid * 16),
            16, 0, 0);
    }
}

// i8-MFMA distance argmin (mfma_i32_32x32x32_i8, K=32): 32 rows/wave, 32 cols/K-step.
// q_x = -4096x, q_e = 4096e as int16 = 256*hi + lo (int8 planes). Four i32 partial
// dots (hh, hl, lh, ll) are EXACT; combine in fp32: dot = (hh*65536 + (hl+lh)*256
// + ll) * 2^-23. Counted-vmcnt barrier: 4 gloads then 4 clamped zero-stores -> vmcnt(4).
__global__ __launch_bounds__(256, 2) void k_argmin(
    const signed char* __restrict__ xh, const signed char* __restrict__ xl,
    const signed char* __restrict__ eh, const signed char* __restrict__ el,
    const float* __restrict__ enorm, int* __restrict__ idx_out,
    int* __restrict__ flagcount, int* __restrict__ flaglist,
    float4* __restrict__ encz, int* __restrict__ counts)
{
    __shared__ __align__(16) signed char smem[2][2][8192];   // 32KB
    const int tid = threadIdx.x;
    const int w = tid >> 6;
    const int lane = tid & 63;
    const int c32 = lane & 31;
    const int h = lane >> 5;
    const int r0 = blockIdx.x * 128 + w * 32;
    const int gtid = blockIdx.x * 256 + tid;      // 0..131071
    const float4 z4 = make_float4(0.f, 0.f, 0.f, 0.f);

    // A fragments: row = lane&31, k = h*16 + j (16 consecutive bytes per ds-chunk)
    intx4 Ah[8], Al[8];
    {
        const signed char* pa = xh + (size_t)(r0 + c32) * D_ + h * 16;
        const signed char* pl = xl + (size_t)(r0 + c32) * D_ + h * 16;
        #pragma unroll
        for (int ds = 0; ds < 8; ++ds) {
            Ah[ds] = *(const intx4*)(pa + ds * 32);
            Al[ds] = *(const intx4*)(pl + ds * 32);
        }
    }

    float b1[16], b2[16];
    int bi[16];
    #pragma unroll
    for (int i = 0; i < 16; ++i) { b1[i] = 3.0e38f; b2[i] = 3.0e38f; bi[i] = 0; }

    // prologue: stage tile 0 into buffer 0
    stage_tile8(eh, el, &smem[0][0][0], &smem[0][1][0], tid);
    __syncthreads();

    // per-lane B read base: col = lane&31 -> h*512 + c32*16 bytes
    const int rb = (h << 9) + (c32 << 4);

    int cb = 0;
    for (int ct = 0; ct < 32; ++ct) {
        if (ct + 1 < 32) {
            stage_tile8(eh + (size_t)(ct + 1) * 8192, el + (size_t)(ct + 1) * 8192,
                        &smem[cb ^ 1][0][0], &smem[cb ^ 1][1][0], tid);
        }
        // pin issue order: all 4 gloads BEFORE the 4 stores (vmcnt retires in order)
        __builtin_amdgcn_sched_barrier(0);
        // background zero-fill of the encodings tail: EXACTLY 4 stores, clamped
        #pragma unroll
        for (int jj = 0; jj < 4; ++jj) {
            int zi = (ct * 4 + jj) * 131072 + gtid;
            zi = (zi < ZTAIL_F4) ? zi : (ZTAIL_F4 - 1);
            encz[zi] = z4;
        }
        const int col = ct * 32 + c32;
        const float en = enorm[col];
        const signed char* sbh = &smem[cb][0][rb];
        const signed char* sbl = &smem[cb][1][rb];
        intx16 hh, m1, m2, ll;
        #pragma unroll
        for (int i = 0; i < 16; ++i) { hh[i] = 0; m1[i] = 0; m2[i] = 0; ll[i] = 0; }
        #pragma unroll
        for (int ds = 0; ds < 8; ++ds) {
            intx4 bh = *(const intx4*)(sbh + ds * 1024);
            intx4 bl = *(const intx4*)(sbl + ds * 1024);
            hh = __builtin_amdgcn_mfma_i32_32x32x32_i8(Ah[ds], bh, hh, 0, 0, 0);
            m1 = __builtin_amdgcn_mfma_i32_32x32x32_i8(Ah[ds], bl, m1, 0, 0, 0);
            m2 = __builtin_amdgcn_mfma_i32_32x32x32_i8(Al[ds], bh, m2, 0, 0, 0);
            ll = __builtin_amdgcn_mfma_i32_32x32x32_i8(Al[ds], bl, ll, 0, 0, 0);
        }
        #pragma unroll
        for (int r = 0; r < 16; ++r) {
            float dot = (float)hh[r] * 65536.0f + (float)(m1[r] + m2[r]) * 256.0f
                      + (float)ll[r];
            float v = en + dot * 1.1920928955078125e-07f;   // * 2^-23
            bool lt = v < b1[r];
            float nb2 = lt ? b1[r] : fminf(v, b2[r]);
            b2[r] = nb2;
            b1[r] = lt ? v : b1[r];
            bi[r] = lt ? col : bi[r];
        }
        // counted-vmcnt barrier: staging loads done, newest 4 stores stay in flight
        asm volatile("s_waitcnt vmcnt(4)" ::: "memory");
        __builtin_amdgcn_sched_barrier(0);
        __builtin_amdgcn_s_barrier();
        __builtin_amdgcn_sched_barrier(0);
        cb ^= 1;
    }

    // LDS is dead: reuse first 4KB as the block histogram
    int* histL = (int*)&smem[0][0][0];
    #pragma unroll
    for (int j = 0; j < 4; ++j) histL[tid + j * 256] = 0;
    __syncthreads();

    #pragma unroll
    for (int r = 0; r < 16; ++r) {
        float B1 = b1[r], B2 = b2[r];
        int Bi = bi[r];
        #pragma unroll
        for (int mask = 1; mask <= 16; mask <<= 1) {
            float v1 = __shfl_xor(B1, mask);
            float v2 = __shfl_xor(B2, mask);
            int i1 = __shfl_xor(Bi, mask);
            if (v1 < B1 || (v1 == B1 && i1 < Bi)) {
                B2 = fminf(fminf(B1, B2), v2);
                B1 = v1; Bi = i1;
            } else {
                B2 = fminf(B2, fminf(v1, v2));
            }
        }
        if (c32 == 0) {
            int row = r0 + (r & 3) + 4 * h + 8 * (r >> 2);
            idx_out[row] = Bi;
            atomicAdd(&histL[Bi], 1);
            if (B2 - B1 < TAU_) {
                int p = atomicAdd(flagcount, 1);
                flaglist[p] = row;
            }
        }
    }
    __syncthreads();
    #pragma unroll
    for (int j = 0; j < 4; ++j) {
        int v = histL[tid + j * 256];
        if (v) atomicAdd(&counts[tid + j * 256], v);
    }
}

// Exact fp64 rescan of flagged (near-tie) rows; incrementally fixes counts.
// Uses precomputed fp64 e-norms (row-invariant) -> inner loop is dot-only (halved FLOPs).
__global__ __launch_bounds__(256) void k_rescan(
    const float* __restrict__ inp, const float* __restrict__ emb,
    const double* __restrict__ enorm64,
    const int* __restrict__ flagcount, const int* __restrict__ flaglist,
    int* __restrict__ idx_out, int* __restrict__ counts)
{
    __shared__ double xd[256];
    __shared__ double sv[256];
    __shared__ int si[256];
    const int tid = threadIdx.x;
    const int nflag = *flagcount;
    for (int f = blockIdx.x; f < nflag; f += gridDim.x) {
        int n = flaglist[f];
        int b = n >> 10, nn = n & 1023;
        xd[tid] = (double)inp[(size_t)b * (C_ * HW_) + (size_t)tid * HW_ + nn];
        __syncthreads();
        double bv = 1e300; int bi = 0;
        for (int k = tid; k < K_; k += 256) {
            const float* ep = emb + (size_t)k * D_;
            double dot = 0.0;
            for (int d = 0; d < D_; ++d) {
                dot = fma(xd[d], (double)ep[d], dot);
            }
            double v = enorm64[k] - 2.0 * dot;
            if (v < bv) { bv = v; bi = k; }
        }
        sv[tid] = bv; si[tid] = bi;
        __syncthreads();
        for (int s = 128; s > 0; s >>= 1) {
            if (tid < s) {
                if (sv[tid + s] < sv[tid] || (sv[tid + s] == sv[tid] && si[tid + s] < si[tid])) {
                    sv[tid] = sv[tid + s]; si[tid] = si[tid + s];
                }
            }
            __syncthreads();
        }
        if (tid == 0) {
            int old = idx_out[n];
            int nw = si[0];
            if (nw != old) {
                idx_out[n] = nw;
                atomicAdd(&counts[old], -1);
                atomicAdd(&counts[nw], 1);
            }
        }
        __syncthreads();
    }
}

// Block-aggregated scatter with local exclusive scan of final counts.
__global__ __launch_bounds__(256) void k_scatter(const int* __restrict__ idx,
                                                 const int* __restrict__ counts,
                                                 int* __restrict__ cursor,
                                                 int* __restrict__ sorted,
                                                 int* __restrict__ offsets) {
    __shared__ int sc[1024];
    __shared__ int hc[1024];
    __shared__ int hb[1024];
    const int tid = threadIdx.x;
    const int base = blockIdx.x * 1024;
    int creg[4];
    #pragma unroll
    for (int j = 0; j < 4; ++j) {
        int k = tid + j * 256;
        creg[j] = counts[k];
        sc[k] = creg[j];
        hc[k] = 0;
    }
    __syncthreads();
    for (int off = 1; off < 1024; off <<= 1) {
        int t0[4];
        #pragma unroll
        for (int j = 0; j < 4; ++j) {
            int k = tid + j * 256;
            t0[j] = (k >= off) ? sc[k - off] : 0;
        }
        __syncthreads();
        #pragma unroll
        for (int j = 0; j < 4; ++j) sc[tid + j * 256] += t0[j];
        __syncthreads();
    }
    #pragma unroll
    for (int j = 0; j < 4; ++j) {
        int k = tid + j * 256;
        sc[k] -= creg[j];
    }
    __syncthreads();
    if (blockIdx.x == 0) {
        #pragma unroll
        for (int j = 0; j < 4; ++j) {
            int k = tid + j * 256;
            offsets[k] = sc[k];
            if (k == 1023) offsets[1024] = sc[1023] + creg[j];
        }
    }
    int myk[4], myn[4];
    #pragma unroll
    for (int j = 0; j < 4; ++j) {
        int n = base + j * 256 + tid;
        myn[j] = n;
        myk[j] = idx[n];
        atomicAdd(&hc[myk[j]], 1);
    }
    __syncthreads();
    #pragma unroll
    for (int j = 0; j < 4; ++j) {
        int kk = tid + j * 256;
        int c = hc[kk];
        hb[kk] = c ? atomicAdd(&cursor[kk], c) : 0;
    }
    __syncthreads();
    #pragma unroll
    for (int j = 0; j < 4; ++j) hc[tid + j * 256] = 0;
    __syncthreads();
    #pragma unroll
    for (int j = 0; j < 4; ++j) {
        int p = sc[myk[j]] + hb[myk[j]] + atomicAdd(&hc[myk[j]], 1);
        sorted[p] = myn[j];
    }
}

// Balanced segmented dw reduction from int8 planes: EXACT int32 accumulation of
// q = 256*xh + xl (= -4096x); dw = -sum(q)/4096 = sum(x).
__global__ __launch_bounds__(256) void k_dwg(const signed char* __restrict__ xh,
                                             const signed char* __restrict__ xl,
                                             const int* __restrict__ sorted,
                                             const int* __restrict__ idx,
                                             const int* __restrict__ offsets,
                                             float* __restrict__ dw) {
    const int lane = threadIdx.x & 63;
    const int wid = threadIdx.x >> 6;
    const int wbase = (blockIdx.x * 4 + wid) * 64;

    int myn = sorted[wbase + lane];
    int myk = idx[myn];

    int4 acc = make_int4(0, 0, 0, 0);
    int cur = __shfl(myk, 0);
    const float sc = -1.0f / 4096.0f;

    #pragma unroll 8
    for (int i = 0; i < 64; ++i) {
        int n = __shfl(myn, i);
        int k = __shfl(myk, i);
        if (k != cur) {
            bool full = (offsets[cur] >= wbase) && (offsets[cur + 1] <= wbase + 64);
            float* dwk = dw + (size_t)cur * D_ + lane * 4;
            if (full) {
                ((float2*)dwk)[0] = make_float2(sc * acc.x, sc * acc.y);
                ((float2*)dwk)[1] = make_float2(sc * acc.z, sc * acc.w);
            } else {
                atomicAdd(dwk + 0, sc * acc.x);
                atomicAdd(dwk + 1, sc * acc.y);
                atomicAdd(dwk + 2, sc * acc.z);
                atomicAdd(dwk + 3, sc * acc.w);
            }
            acc = make_int4(0, 0, 0, 0);
            cur = k;
        }
        size_t o = (size_t)n * D_ + lane * 4;
        char4 hx = *(const char4*)(xh + o);
        char4 lx = *(const char4*)(xl + o);
        acc.x += ((int)hx.x << 8) + (int)lx.x;
        acc.y += ((int)hx.y << 8) + (int)lx.y;
        acc.z += ((int)hx.z << 8) + (int)lx.z;
        acc.w += ((int)hx.w << 8) + (int)lx.w;
    }
    {
        bool full = (offsets[cur] >= wbase) && (offsets[cur + 1] <= wbase + 64);
        float* dwk = dw + (size_t)cur * D_ + lane * 4;
        if (full) {
            ((float2*)dwk)[0] = make_float2(sc * acc.x, sc * acc.y);
            ((float2*)dwk)[1] = make_float2(sc * acc.z, sc * acc.w);
        } else {
            atomicAdd(dwk + 0, sc * acc.x);
            atomicAdd(dwk + 1, sc * acc.y);
            atomicAdd(dwk + 2, sc * acc.z);
            atomicAdd(dwk + 3, sc * acc.w);
        }
    }
}

// Quantize + loss (LDS-transposed embedding gather) + folded head-zero.
__global__ __launch_bounds__(256) void k_quant(
    const float* __restrict__ inp, const float* __restrict__ emb,
    const int* __restrict__ idx, float* __restrict__ outp, float* __restrict__ losssum,
    float* __restrict__ enc)
{
    __shared__ float qt[64][260];
    __shared__ int karr[64];
    __shared__ float red[256];
    const int tid = threadIdx.x;
    const int bid = blockIdx.x;        // 1024 blocks: b(64) x hwtile(16)
    const int b = bid >> 4;
    const int ht = bid & 15;
    const int base_n = b * HW_ + ht * 64;

    {
        const float4 z4 = make_float4(0.f, 0.f, 0.f, 0.f);
        float4* pz = (float4*)(enc + 2);
        int t = bid * 256 + tid;       // 262144 threads
        #pragma unroll
        for (int it = 0; it < 9; ++it) {
            int i = it * 262144 + t;
            if (i < ZHEAD_F4) pz[i] = z4;
        }
        if (t == 0) { enc[0] = 0.f; enc[1] = 0.f; enc[67108862] = 0.f; enc[67108863] = 0.f; }
    }

    if (tid < 64) karr[tid] = idx[base_n + tid];
    __syncthreads();

    #pragma unroll
    for (int it = 0; it < 16; ++it) {
        int f = it * 256 + tid;
        int r = f >> 6;
        int c4 = (f & 63) << 2;
        float4 v = ((const float4*)emb)[karr[r] * 64 + (c4 >> 2)];
        *(float4*)(&qt[r][c4]) = v;
    }
    __syncthreads();

    float s = 0.0f;
    #pragma unroll
    for (int it = 0; it < 16; ++it) {
        int f = it * 256 + tid;
        int c = f >> 4;
        int hl = (f & 15) << 2;
        int g = b * 65536 + c * 256 + ht * 16 + (hl >> 2);
        float4 x = ((const float4*)inp)[g];
        float q0 = qt[hl + 0][c];
        float q1 = qt[hl + 1][c];
        float q2 = qt[hl + 2][c];
        float q3 = qt[hl + 3][c];
        float d0 = q0 - x.x, d1 = q1 - x.y, d2 = q2 - x.z, d3 = q3 - x.w;
        ((float4*)outp)[g] = make_float4(x.x + d0, x.y + d1, x.z + d2, x.w + d3);
        s += d0 * d0 + d1 * d1 + d2 * d2 + d3 * d3;
    }
    red[tid] = s;
    __syncthreads();
    for (int t = 128; t > 0; t >>= 1) {
        if (tid < t) red[tid] += red[tid + t];
        __syncthreads();
    }
    if (tid == 0) atomicAdd(losssum, red[0]);
}

// Final fused kernel: cluster EMA, ema_w/new_embedding, loss+entropy, one-hot writes.
__global__ __launch_bounds__(256) void k_fin(
    const float* __restrict__ ema_cs, const int* __restrict__ counts,
    const float* __restrict__ losssum, const float* __restrict__ ema_w,
    const int* __restrict__ idx,
    float* __restrict__ neww, float* __restrict__ newemb,
    float* __restrict__ out_cluster, float* __restrict__ out_loss,
    float* __restrict__ out_ent, float* __restrict__ enc)
{
    __shared__ float sraw[1024];
    __shared__ float red[256];
    __shared__ float sclv;
    const int tid = threadIdx.x;
    const int bid = blockIdx.x;
    float part = 0.f;
    float ent = 0.f;
    #pragma unroll
    for (int j = 0; j < 4; ++j) {
        int k = tid + j * 256;
        float cnt = (float)counts[k];
        float raw = ema_cs[k] * DECAY_ + OMD_ * cnt;
        sraw[k] = raw;
        part += raw;
        float p = cnt * (1.0f / 65536.0f);
        ent += p * logf(p + 1e-10f);
    }
    red[tid] = part;
    __syncthreads();
    for (int t = 128; t > 0; t >>= 1) {
        if (tid < t) red[tid] += red[tid + t];
        __syncthreads();
    }
    float nsum = red[0];
    __syncthreads();
    red[tid] = ent;
    __syncthreads();
    for (int t = 128; t > 0; t >>= 1) {
        if (tid < t) red[tid] += red[tid + t];
        __syncthreads();
    }
    if (tid == 0) {
        float clv = (sraw[bid] + EPS_) / (nsum + 1024.0f * EPS_) * nsum;
        sclv = clv;
        out_cluster[bid] = clv;
        if (bid == 0) {
            out_ent[0] = -red[0];
            out_loss[0] = 0.25f * losssum[0] * (1.0f / 16777216.0f);
        }
    }
    __syncthreads();
    float clv = sclv;
    int g = bid * 256 + tid;
    float w = ema_w[g] * DECAY_ + OMD_ * neww[g];
    neww[g] = w;
    newemb[g] = w / clv;
    if (tid < 64) {
        int n = bid * 64 + tid;
        enc[(size_t)n * 1024 + idx[n]] = 1.0f;
    }
}

extern "C" void kernel_launch(void* const* d_in, const int* in_sizes, int n_in,
                              void* d_out, int out_size, void* d_ws, size_t ws_size,
                              hipStream_t stream)
{
    const float* inp    = (const float*)d_in[0];
    const float* emb    = (const float*)d_in[1];
    const float* ema_cs = (const float*)d_in[2];
    const float* ema_w  = (const float*)d_in[3];

    float* out0        = (float*)d_out;
    float* out_loss    = out0 + OFF_LOSS;
    float* out_ent     = out0 + OFF_ENT;
    float* out_enc     = out0 + OFF_ENC;
    float* out_cluster = out0 + OFF_CLUSTER;
    float* out_neww    = out0 + OFF_NEWW;
    float* out_newemb  = out0 + OFF_NEWEMB;

    signed char* ws_xh = (signed char*)(out0 + OFF_XH);
    signed char* ws_xl = (signed char*)(out0 + OFF_XL);
    signed char* ws_eh = (signed char*)(out0 + OFF_EH);
    signed char* ws_el = (signed char*)(out0 + OFF_EL);
    int*   ws_sorted  = (int*)(out0 + OFF_SORT2);
    int*   ws_offsets = ws_sorted + 65536;
    int*   ws_cursor  = ws_offsets + 1025;

    int*   ws_idx    = (int*)d_ws;
    int*   ws_counts = ws_idx + 65536;
    int*   ws_flagc  = ws_idx + 66560;
    float* ws_loss   = (float*)(ws_idx + 66561);
    int*   ws_flagl  = ws_idx + 66562;
    float* ws_enorm  = (float*)(ws_idx + 132098);             // fp32[1024]
    double* ws_enorm64 = (double*)(ws_idx + 133124);          // fp64[1024], 8B-aligned

    float4* encz = (float4*)(out0 + ZTAIL_ABS);

    k_prep_e <<<1024, 64, 0, stream>>>(emb, ws_eh, ws_el, ws_enorm, ws_enorm64);
    k_prep_x <<<2048, 256, 0, stream>>>(inp, ws_xh, ws_xl, out_neww, ws_counts, ws_cursor);
    k_argmin <<<512, 256, 0, stream>>>(ws_xh, ws_xl, ws_eh, ws_el, ws_enorm,
                                       ws_idx, ws_flagc, ws_flagl, encz, ws_counts);
    k_rescan <<<256, 256, 0, stream>>>(inp, emb, ws_enorm64, ws_flagc, ws_flagl, ws_idx, ws_counts);
    k_scatter<<<64, 256, 0, stream>>>(ws_idx, ws_counts, ws_cursor, ws_sorted, ws_offsets);
    k_dwg    <<<256, 256, 0, stream>>>(ws_xh, ws_xl, ws_sorted, ws_idx, ws_offsets, out_neww);
    k_quant  <<<1024, 256, 0, stream>>>(inp, emb, ws_idx, out0, ws_loss, out_enc);
    k_fin    <<<1024, 256, 0, stream>>>(ema_cs, ws_counts, ws_loss, ema_w, ws_idx,
                                        out_neww, out_newemb, out_cluster, out_loss,
                                        out_ent, out_enc);
}